// Round 13
// baseline (97.945 us; speedup 1.0000x reference)
//
#include <hip/hip_runtime.h>
#include <stdint.h>

// Problem constants
constexpr int ROWS = 64;
constexpr int D = 1 << 19;             // 524288 per row
constexpr uint32_t KSEL = 52428;       // int(0.1 * D)
constexpr int MBPR = 32;               // blocks per row for streaming kernels
constexpr int MCHUNK = D / MBPR;       // 16384 elements per block
constexpr int WCAP = 224;              // per-wave slot cap (mean ~86, +15 sigma)
constexpr int LBUF = 4 * WCAP;         // per-block slot cap = 896 (layout as R12)
constexpr uint32_t PRED_B = 0xBFAu;    // key bucket of floats [1.25, 1.375);
                                       // K-th largest = 1.2816 +- 0.0024 (13/39 sigma margin)
constexpr uint32_t NCAND_MAX = 12288;  // per-row candidate cap (mean ~11.1K, +11.6 sigma)
constexpr uint32_t OVF = 0x80000000u;  // overflow marker in SCNT

// Workspace layout (u32 words). No zeroing needed: counts plain-stored fresh
// every call; slots read only up to their stored count; thr rewritten always.
constexpr size_t OFF_SCNT = 0;         // [2048] per-block count (| OVF bit)
constexpr size_t OFF_ACNT = 2048;      // [2048] per-block above-bucket count
constexpr size_t OFF_THR  = 4096;      // [64] exact threshold key per row
constexpr size_t OFF_PAIR = 4160;      // [2048][2*LBUF]: keys[LBUF] then idx[LBUF]

typedef float f32x4 __attribute__((ext_vector_type(4)));

// Monotonic key: larger float -> larger uint
__device__ __forceinline__ uint32_t mono(uint32_t f) {
    uint32_t m = (uint32_t)((int32_t)f >> 31) | 0x80000000u;
    return f ^ m;
}

// Kernel 1 (read-only): candidate collection + above-count, ATOMIC-FREE.
// Each wave collects into a private LDS segment via ballot-compaction;
// branch is wave-uniform (execz-skipped when no lane matches).
__global__ __launch_bounds__(256) void cand_scan(const uint32_t* __restrict__ x,
                                                 uint32_t* __restrict__ ws) {
    __shared__ uint32_t lkey[4][WCAP];
    __shared__ uint32_t lidx[4][WCAP];
    __shared__ uint32_t wcnt[4];       // raw per-wave counts (wave-private RMW)
    __shared__ uint32_t pre[4];        // stored-count prefix
    __shared__ uint32_t red[256];
    const int bid = blockIdx.x;
    const int row = bid / MBPR, chunk = bid % MBPR, t = threadIdx.x;
    const int w = t >> 6, lane = t & 63;
    if (lane == 0) wcnt[w] = 0;
    __syncthreads();
    const uint64_t lt = ((uint64_t)1 << lane) - 1;
    const uint4* __restrict__ p = (const uint4*)(x + (size_t)row * D + (size_t)chunk * MCHUNK);
    uint32_t above = 0;

    for (int ii = 0; ii < 8; ++ii) {
        const int i0 = ii * 512 + t;
        uint4 v0 = p[i0];
        uint4 v1 = p[i0 + 256];        // 2 loads in flight, no stores in loop
#define CLS(comp, idxv)                                                     \
        {                                                                   \
            uint32_t u = mono(comp);                                        \
            uint32_t bu = u >> 20;                                          \
            above += (bu > PRED_B);                                         \
            bool mtc = (bu == PRED_B);                                      \
            uint64_t bal = __ballot(mtc);                                   \
            if (bal) {  /* wave-uniform branch */                           \
                uint32_t base = wcnt[w];                                    \
                if (mtc) {                                                  \
                    uint32_t s = base + (uint32_t)__popcll(bal & lt);       \
                    if (s < (uint32_t)WCAP) { lkey[w][s] = u; lidx[w][s] = idxv; } \
                }                                                           \
                if (lane == 0) wcnt[w] = base + (uint32_t)__popcll(bal);    \
            }                                                               \
        }
        {
            uint32_t b0 = (uint32_t)chunk * MCHUNK + (uint32_t)i0 * 4;
            CLS(v0.x, b0 + 0) CLS(v0.y, b0 + 1) CLS(v0.z, b0 + 2) CLS(v0.w, b0 + 3)
            uint32_t b1 = (uint32_t)chunk * MCHUNK + (uint32_t)(i0 + 256) * 4;
            CLS(v1.x, b1 + 0) CLS(v1.y, b1 + 1) CLS(v1.z, b1 + 2) CLS(v1.w, b1 + 3)
        }
#undef CLS
    }

    red[t] = above;
    __syncthreads();
    for (int off = 128; off > 0; off >>= 1) {
        if (t < off) red[t] += red[t + off];
        __syncthreads();
    }
    if (t == 0) {
        uint32_t acc = 0, raw = 0, ovf = 0;
        for (int i = 0; i < 4; ++i) {
            uint32_t r = wcnt[i];
            pre[i] = acc;
            uint32_t st = r < (uint32_t)WCAP ? r : (uint32_t)WCAP;
            acc += st;
            raw += r;
            ovf |= (r > (uint32_t)WCAP) ? OVF : 0u;
        }
        ws[OFF_SCNT + bid] = raw | ovf;   // raw total; OVF set if any wave spilled
        ws[OFF_ACNT + bid] = red[0];
    }
    __syncthreads();
    // each wave copies its segment to the block's compact slot region
    {
        uint32_t r = wcnt[w];
        uint32_t st = r < (uint32_t)WCAP ? r : (uint32_t)WCAP;
        uint32_t b = pre[w];
        uint32_t* sk = ws + OFF_PAIR + (size_t)bid * (2 * LBUF);
        for (uint32_t i = lane; i < st; i += 64) {
            sk[b + i] = lkey[w][i];
            sk[LBUF + b + i] = lidx[w][i];
        }
    }
}

// Kernel 2, one block per row: compute the EXACT threshold key.
// Valid path: gather candidate keys to LDS, two-level radix-select
// (rank = KSEL - above). Invalid path (prediction wrong / overflow):
// 3-pass histogram select over the row.
__global__ __launch_bounds__(256) void select_thr(const uint32_t* __restrict__ x,
                                                  uint32_t* __restrict__ ws) {
    __shared__ uint32_t ckey[NCAND_MAX];  // 48 KB; fallback reuses [0..4096) as hist
    __shared__ uint32_t h[1024];
    __shared__ uint32_t sc[256];
    __shared__ uint32_t soff[MBPR + 1];
    __shared__ uint32_t scnt_s[MBPR];
    __shared__ uint32_t acnt_s[MBPR];
    __shared__ uint32_t bc[3];
    const int row = blockIdx.x, t = threadIdx.x;

    if (t < MBPR) {
        scnt_s[t] = ws[OFF_SCNT + (size_t)row * MBPR + t];
        acnt_s[t] = ws[OFF_ACNT + (size_t)row * MBPR + t];
    }
    __syncthreads();
    if (t == 0) {
        uint32_t acc = 0, ab = 0, ovf = 0;
        for (int s = 0; s < MBPR; ++s) {
            uint32_t c = scnt_s[s];
            ovf |= c & OVF;
            soff[s] = acc;
            acc += c & ~OVF;
            ab += acnt_s[s];
        }
        soff[MBPR] = acc;
        bc[0] = acc;  // n candidates (raw; == stored iff no ovf)
        bc[1] = ab;   // count strictly above bucket
        bc[2] = (!ovf && acc <= NCAND_MAX && ab < KSEL && ab + acc >= KSEL) ? 1u : 0u;
    }
    __syncthreads();
    const uint32_t n = bc[0], above = bc[1], valid = bc[2];

    if (valid) {
        const uint32_t k = KSEL - above;  // rank among candidates, 1-based
        for (int s = 0; s < MBPR; ++s) {
            uint32_t cnt = soff[s + 1] - soff[s];
            const uint32_t* sk = ws + OFF_PAIR + ((size_t)row * MBPR + s) * (2 * LBUF);
            for (uint32_t i = t; i < cnt; i += 256) ckey[soff[s] + i] = sk[i];
        }
        // Level 1: bits 19..10
        for (int i = t; i < 1024; i += 256) h[i] = 0;
        __syncthreads();
        for (uint32_t i = t; i < n; i += 256) atomicAdd(&h[(ckey[i] >> 10) & 0x3FFu], 1u);
        __syncthreads();
        {
            int hi = 1023 - t * 4;
            uint32_t s = 0;
            for (int j = 0; j < 4; ++j) s += h[hi - j];
            sc[t] = s;
            __syncthreads();
            for (int off = 1; off < 256; off <<= 1) {
                uint32_t v = (t >= off) ? sc[t - off] : 0u;
                __syncthreads();
                sc[t] += v;
                __syncthreads();
            }
            uint32_t excl = sc[t] - s;
            if (excl < k && excl + s >= k) {
                uint32_t cc = excl;
                for (int j = 0; j < 4; ++j) {
                    int bin = hi - j;
                    uint32_t hb = h[bin];
                    cc += hb;
                    if (cc >= k) { bc[0] = (uint32_t)bin; bc[1] = k - (cc - hb); break; }
                }
            }
        }
        __syncthreads();
        uint32_t b1 = bc[0], k2 = bc[1];
        __syncthreads();
        // Level 2: bits 9..0
        for (int i = t; i < 1024; i += 256) h[i] = 0;
        __syncthreads();
        for (uint32_t i = t; i < n; i += 256) {
            uint32_t u = ckey[i];
            if (((u >> 10) & 0x3FFu) == b1) atomicAdd(&h[u & 0x3FFu], 1u);
        }
        __syncthreads();
        {
            int hi = 1023 - t * 4;
            uint32_t s = 0;
            for (int j = 0; j < 4; ++j) s += h[hi - j];
            sc[t] = s;
            __syncthreads();
            for (int off = 1; off < 256; off <<= 1) {
                uint32_t v = (t >= off) ? sc[t - off] : 0u;
                __syncthreads();
                sc[t] += v;
                __syncthreads();
            }
            uint32_t excl = sc[t] - s;
            if (excl < k2 && excl + s >= k2) {
                uint32_t cc = excl;
                for (int j = 0; j < 4; ++j) {
                    int bin = hi - j;
                    uint32_t hb = h[bin];
                    cc += hb;
                    if (cc >= k2) {
                        ws[OFF_THR + row] = (PRED_B << 20) | (b1 << 10) | (uint32_t)bin;
                        break;
                    }
                }
            }
        }
        return;
    }

    // ---------- exact fallback (prediction failed; any-data correct) ----------
    const uint4* px = (const uint4*)(x + (size_t)row * D);
    uint32_t* h4k = ckey;  // reuse 16 KB of ckey as 4096-bin hist

    // Pass A: 4096-bin hist of top 12 key bits -> bucket B + rank r1
    for (int i = t; i < 4096; i += 256) h4k[i] = 0;
    __syncthreads();
    for (int i = t; i < D / 4; i += 256) {
        uint4 v = px[i];
        atomicAdd(&h4k[mono(v.x) >> 20], 1u);
        atomicAdd(&h4k[mono(v.y) >> 20], 1u);
        atomicAdd(&h4k[mono(v.z) >> 20], 1u);
        atomicAdd(&h4k[mono(v.w) >> 20], 1u);
    }
    __syncthreads();
    {
        int hi = 4095 - t * 16;
        uint32_t loc[16];
        uint32_t s = 0;
#pragma unroll
        for (int j = 0; j < 16; ++j) { loc[j] = h4k[hi - j]; s += loc[j]; }
        sc[t] = s;
        __syncthreads();
        for (int off = 1; off < 256; off <<= 1) {
            uint32_t v = (t >= off) ? sc[t - off] : 0u;
            __syncthreads();
            sc[t] += v;
            __syncthreads();
        }
        uint32_t excl = sc[t] - s;
        if (excl < KSEL && excl + s >= KSEL) {
            uint32_t c = excl;
            for (int j = 0; j < 16; ++j) {
                c += loc[j];
                if (c >= KSEL) { bc[0] = (uint32_t)(hi - j); bc[1] = KSEL - (c - loc[j]); break; }
            }
        }
    }
    __syncthreads();
    const uint32_t B = bc[0], r1 = bc[1];
    __syncthreads();

    // Pass B: bits 19..10 among bucket == B -> b1, r2
    for (int i = t; i < 1024; i += 256) h[i] = 0;
    __syncthreads();
    for (int i = t; i < D / 4; i += 256) {
        uint4 v = px[i];
        uint32_t u;
        u = mono(v.x); if ((u >> 20) == B) atomicAdd(&h[(u >> 10) & 0x3FFu], 1u);
        u = mono(v.y); if ((u >> 20) == B) atomicAdd(&h[(u >> 10) & 0x3FFu], 1u);
        u = mono(v.z); if ((u >> 20) == B) atomicAdd(&h[(u >> 10) & 0x3FFu], 1u);
        u = mono(v.w); if ((u >> 20) == B) atomicAdd(&h[(u >> 10) & 0x3FFu], 1u);
    }
    __syncthreads();
    {
        int hi = 1023 - t * 4;
        uint32_t s = 0;
        for (int j = 0; j < 4; ++j) s += h[hi - j];
        sc[t] = s;
        __syncthreads();
        for (int off = 1; off < 256; off <<= 1) {
            uint32_t v = (t >= off) ? sc[t - off] : 0u;
            __syncthreads();
            sc[t] += v;
            __syncthreads();
        }
        uint32_t excl = sc[t] - s;
        if (excl < r1 && excl + s >= r1) {
            uint32_t cc = excl;
            for (int j = 0; j < 4; ++j) {
                int bin = hi - j;
                uint32_t hb = h[bin];
                cc += hb;
                if (cc >= r1) { bc[0] = (uint32_t)bin; bc[1] = r1 - (cc - hb); break; }
            }
        }
    }
    __syncthreads();
    const uint32_t pref22 = (B << 10) | bc[0];
    const uint32_t r2 = bc[1];
    __syncthreads();

    // Pass C: bits 9..0 among (u>>10) == pref22 -> thr_key
    for (int i = t; i < 1024; i += 256) h[i] = 0;
    __syncthreads();
    for (int i = t; i < D / 4; i += 256) {
        uint4 v = px[i];
        uint32_t u;
        u = mono(v.x); if ((u >> 10) == pref22) atomicAdd(&h[u & 0x3FFu], 1u);
        u = mono(v.y); if ((u >> 10) == pref22) atomicAdd(&h[u & 0x3FFu], 1u);
        u = mono(v.z); if ((u >> 10) == pref22) atomicAdd(&h[u & 0x3FFu], 1u);
        u = mono(v.w); if ((u >> 10) == pref22) atomicAdd(&h[u & 0x3FFu], 1u);
    }
    __syncthreads();
    {
        int hi = 1023 - t * 4;
        uint32_t s = 0;
        for (int j = 0; j < 4; ++j) s += h[hi - j];
        sc[t] = s;
        __syncthreads();
        for (int off = 1; off < 256; off <<= 1) {
            uint32_t v = (t >= off) ? sc[t - off] : 0u;
            __syncthreads();
            sc[t] += v;
            __syncthreads();
        }
        uint32_t excl = sc[t] - s;
        if (excl < r2 && excl + s >= r2) {
            uint32_t cc = excl;
            for (int j = 0; j < 4; ++j) {
                int bin = hi - j;
                uint32_t hb = h[bin];
                cc += hb;
                if (cc >= r2) { ws[OFF_THR + row] = (pref22 << 10) | (uint32_t)bin; break; }
            }
        }
    }
}

// Kernel 3: pure streaming masked copy against the EXACT per-row threshold.
// Zero LDS, zero atomics, 2-deep load pipeline; NT stores.
__global__ __launch_bounds__(256) void mask_final(const uint32_t* __restrict__ x,
                                                  float* __restrict__ out,
                                                  const uint32_t* __restrict__ ws) {
    const int bid = blockIdx.x;
    const int row = bid / MBPR, chunk = bid % MBPR, t = threadIdx.x;
    const uint32_t tk = ws[OFF_THR + row];
    const uint4* __restrict__ p = (const uint4*)(x + (size_t)row * D + (size_t)chunk * MCHUNK);
    f32x4* __restrict__ o = (f32x4*)(out + (size_t)row * D + (size_t)chunk * MCHUNK);
    for (int ii = 0; ii < 8; ++ii) {
        const int i0 = ii * 512 + t;
        uint4 v0 = p[i0];
        uint4 v1 = p[i0 + 256];
        f32x4 a, b;
        a[0] = (mono(v0.x) < tk) ? __uint_as_float(v0.x) : 0.0f;
        a[1] = (mono(v0.y) < tk) ? __uint_as_float(v0.y) : 0.0f;
        a[2] = (mono(v0.z) < tk) ? __uint_as_float(v0.z) : 0.0f;
        a[3] = (mono(v0.w) < tk) ? __uint_as_float(v0.w) : 0.0f;
        b[0] = (mono(v1.x) < tk) ? __uint_as_float(v1.x) : 0.0f;
        b[1] = (mono(v1.y) < tk) ? __uint_as_float(v1.y) : 0.0f;
        b[2] = (mono(v1.z) < tk) ? __uint_as_float(v1.z) : 0.0f;
        b[3] = (mono(v1.w) < tk) ? __uint_as_float(v1.w) : 0.0f;
        __builtin_nontemporal_store(a, &o[i0]);
        __builtin_nontemporal_store(b, &o[i0 + 256]);
    }
}

extern "C" void kernel_launch(void* const* d_in, const int* in_sizes, int n_in,
                              void* d_out, int out_size, void* d_ws, size_t ws_size,
                              hipStream_t stream) {
    (void)in_sizes; (void)n_in; (void)out_size; (void)ws_size;
    const uint32_t* xu = (const uint32_t*)d_in[0];
    float* outp = (float*)d_out;
    uint32_t* ws = (uint32_t*)d_ws;

    cand_scan<<<ROWS * MBPR, 256, 0, stream>>>(xu, ws);
    select_thr<<<ROWS, 256, 0, stream>>>(xu, ws);
    mask_final<<<ROWS * MBPR, 256, 0, stream>>>(xu, outp, ws);
}